// Round 12
// baseline (119.881 us; speedup 1.0000x reference)
//
#include <hip/hip_runtime.h>

typedef unsigned int uint;
typedef unsigned short ushort;
typedef __attribute__((ext_vector_type(4))) uint   u32x4;
typedef __attribute__((ext_vector_type(8))) short  short8;
typedef __attribute__((ext_vector_type(8))) __bf16 bf16x8;
typedef __attribute__((ext_vector_type(4))) float  f32x4;

// Device pass: real gfx950 builtin. Host pass: inert asm fallback (never codegen'd).
__device__ __forceinline__ f32x4 mfma32(short8 a, short8 b, f32x4 c){
#if __has_builtin(__builtin_amdgcn_mfma_f32_16x16x32_bf16)
    return __builtin_amdgcn_mfma_f32_16x16x32_bf16(
        __builtin_bit_cast(bf16x8, a), __builtin_bit_cast(bf16x8, b), c, 0, 0, 0);
#else
    asm volatile("v_mfma_f32_16x16x32_bf16 %0, %1, %2, %0\n\ts_nop 7\n\ts_nop 7"
                 : "+v"(c) : "v"(a), "v"(b));
    return c;
#endif
}

__device__ __forceinline__ uint  fbits(float f){ return __builtin_bit_cast(uint, f); }
__device__ __forceinline__ float ibits(uint u){ return __builtin_bit_cast(float, u); }
__device__ __forceinline__ ushort rne_bf16(float f){
    uint u = fbits(f);
    return (ushort)((u + 0x7FFFu + ((u >> 16) & 1u)) >> 16);
}
// packed 2xf32 -> 2xbf16 (low = a, high = b); single HW op on gfx950
__device__ __forceinline__ uint cvtpk(float a, float b){
    uint r;
    asm("v_cvt_pk_bf16_f32 %0, %1, %2" : "=v"(r) : "v"(a), "v"(b));
    return r;
}

// ---------------- weight packing into per-lane K=32 MFMA fragments ----------------
// Slot convention (valid because A and B share the same (g,e)->k map, so the HW
// k-permutation cancels): slot (g=lane>>4, e=0..7) of the K=32 operand.
//  A1[t]: slot e -> channel c = 4g+(e&3); part = (e<4) ? hi : lo of W1[c][16t+m]
//  A2[p]: slot e -> hidden  = 16*(2p+(e>>2)) + 4g + (e&3); value = bf16(W2[hid][m])
//  b1f[t]: f32x4 = b1[16t+4g+r]  (C-in bias for layer 1)
// ws u32 layout: [0..1023] A1 (t*64+l)*4+reg ; [1024..1535] A2 (p*64+l)*4+reg ;
//                [1536..2559] b1f as f32 (t*64+l)*4+r
__global__ void pack_weights(const float* __restrict__ W1, const float* __restrict__ b1,
                             const float* __restrict__ W2, float* __restrict__ ws)
{
    const int e4 = threadIdx.x;         // 256 = 4 tiles * 64 lanes
    const int t = e4 >> 6, l = e4 & 63;
    const int g = l >> 4, m = l & 15;
    uint* wsu = (uint*)ws;

    // A1 tile t: hi part in K-half 0 (e=0..3), lo residual in K-half 1 (e=4..7)
    ushort el[8];
    #pragma unroll
    for (int i = 0; i < 8; ++i) {
        const int c = 4*g + (i & 3);
        const float w = W1[c * 64 + 16*t + m];   // W1 is (16,64) row-major
        const ushort hi = rne_bf16(w);
        if (i < 4) el[i] = hi;
        else       el[i] = rne_bf16(w - ibits(((uint)hi) << 16));  // lo residual
    }
    #pragma unroll
    for (int r = 0; r < 4; ++r)
        wsu[(t*64 + l)*4 + r] = (uint)el[2*r] | ((uint)el[2*r+1] << 16);

    // A2 pair p (only t<2): two 16-hidden tiles per K=32
    if (t < 2) {
        const int p = t;
        ushort e2[8];
        #pragma unroll
        for (int i = 0; i < 8; ++i) {
            const int hid = 16*(2*p + (i >> 2)) + 4*g + (i & 3);
            e2[i] = rne_bf16(W2[hid * 16 + m]);  // W2 is (64,16) row-major
        }
        #pragma unroll
        for (int r = 0; r < 4; ++r)
            wsu[1024 + (p*64 + l)*4 + r] = (uint)e2[2*r] | ((uint)e2[2*r+1] << 16);
    }

    // b1 fragment
    #pragma unroll
    for (int r = 0; r < 4; ++r)
        ws[1536 + (t*64 + l)*4 + r] = b1[16*t + 4*g + r];
}

// ---------------- main kernel ----------------
// One wave = 16 rows; lane (n=l&15, g=l>>4) owns row n, channel window 4g..4g+3.
// Per neighbor: 4 independent K=32 MFMAs for layer 1 (W1 hi+lo packed into the
// two K-halves, x_hi duplicated), relu+cvt_pk, then 2 chained K=32 MFMAs for
// layer 2 whose B-fragment is exactly the packed layer-1 output -- zero
// cross-lane movement anywhere. 6 MFMAs/neighbor.
// ROUND 12: the kernel is a compulsory 487-MB stream (each input byte read
// exactly once); at 97us we deliver 5.0 TB/s = 80% of the 6.3 TB/s streaming
// ceiling. The 26% gap is the waves_per_eu(4,4) residency cap (occupancy stuck
// at ~40% since r5). Relax to min-6/no-max: live set ~52 regs -> allocator can
// land <=64 and the HW runs 8 waves/SIMD. r2/r6 spill mode needs live>budget;
// 52 << 85 so that failure is excluded. WRITE_SIZE ~16.4 MB is the tripwire.
__global__ __launch_bounds__(256) __attribute__((amdgpu_waves_per_eu(6)))
void subattn_mfma(const float* __restrict__ q, const float* __restrict__ k,
                  const float* __restrict__ v, const float* __restrict__ pe,
                  const float* __restrict__ ws, float* __restrict__ out)
{
    const int tid = threadIdx.x;
    const int wv  = tid >> 6;
    const int l   = tid & 63;
    const int n   = l & 15, g = l >> 4;
    const int grp = blockIdx.x * 4 + wv;
    const int rg  = grp * 16 + n;            // global row = bp*4 + h
    const int bp  = rg >> 2, h = rg & 3;

    // weight fragments: A1 16 + A2 8 + b1f 16 = 40 VGPRs persistent
    const u32x4* a1p = (const u32x4*)ws;
    const u32x4* a2p = (const u32x4*)(ws + 1024);
    const f32x4* bfp = (const f32x4*)(ws + 1536);
    short8 a1[4], a2[2];
    f32x4  b1f[4];
    #pragma unroll
    for (int t = 0; t < 4; ++t) {
        a1[t]  = __builtin_bit_cast(short8, a1p[t*64 + l]);
        b1f[t] = bfp[t*64 + l];
    }
    #pragma unroll
    for (int p = 0; p < 2; ++p) a2[p] = __builtin_bit_cast(short8, a2p[p*64 + l]);

    const size_t qoff  = (size_t)rg * 16 + g * 4;
    const f32x4  qf    = *(const f32x4*)(q + qoff);
    const size_t kbase = (size_t)bp * 576 + h * 16 + g * 4;   // 9*64 per bp

    f32x4 lsum = {0.f, 0.f, 0.f, 0.f};
    f32x4 acc  = {0.f, 0.f, 0.f, 0.f};

    // 1-deep pipeline: k/pe of neighbor 0
    f32x4 kf = *(const f32x4*)(k  + kbase);
    f32x4 pf = *(const f32x4*)(pe + kbase);

    for (int j = 0; j < 9; ++j) {
        f32x4 kn, pn;
        if (j < 8) {
            const size_t noff = kbase + (size_t)(j + 1) * 64;
            kn = *(const f32x4*)(k  + noff);
            pn = *(const f32x4*)(pe + noff);
        }
        const f32x4 vf = *(const f32x4*)(v + kbase + (size_t)j * 64);

        const f32x4 x = qf - kf + pf;
        const uint xp0 = cvtpk(x.x, x.y);
        const uint xp1 = cvtpk(x.z, x.w);
        const u32x4 bxu = {xp0, xp1, xp0, xp1};        // [x_hi | x_hi] K-halves
        const short8 bx = __builtin_bit_cast(short8, bxu);

        // layer 1: 4 independent MFMAs, bias as C-in
        f32x4 c1_0 = mfma32(a1[0], bx, b1f[0]);
        f32x4 c1_1 = mfma32(a1[1], bx, b1f[1]);
        f32x4 c1_2 = mfma32(a1[2], bx, b1f[2]);
        f32x4 c1_3 = mfma32(a1[3], bx, b1f[3]);

        // relu + pack to bf16: ph[t] = h[n][16t+4g+{0,1,2,3}]
        uint ph[4][2];
        {
            f32x4 c1s[4] = {c1_0, c1_1, c1_2, c1_3};
            #pragma unroll
            for (int t = 0; t < 4; ++t) {
                const float r0 = fmaxf(c1s[t].x, 0.f), r1 = fmaxf(c1s[t].y, 0.f);
                const float r2 = fmaxf(c1s[t].z, 0.f), r3 = fmaxf(c1s[t].w, 0.f);
                ph[t][0] = cvtpk(r0, r1);
                ph[t][1] = cvtpk(r2, r3);
            }
        }

        // layer 2: B-fragment = concatenated layer-1 outputs (no shuffles)
        const u32x4 bh0u = {ph[0][0], ph[0][1], ph[1][0], ph[1][1]};
        const u32x4 bh1u = {ph[2][0], ph[2][1], ph[3][0], ph[3][1]};
        f32x4 c2 = {0.f, 0.f, 0.f, 0.f};
        c2 = mfma32(a2[0], __builtin_bit_cast(short8, bh0u), c2);
        c2 = mfma32(a2[1], __builtin_bit_cast(short8, bh1u), c2);
        // b2 omitted: softmax over neighbors is shift-invariant in b2.

        const f32x4 vp = vf + pf;
        const float e0 = __expf(c2.x), e1 = __expf(c2.y);
        const float e2 = __expf(c2.z), e3 = __expf(c2.w);
        lsum.x += e0; lsum.y += e1; lsum.z += e2; lsum.w += e3;
        acc.x = fmaf(e0, vp.x, acc.x); acc.y = fmaf(e1, vp.y, acc.y);
        acc.z = fmaf(e2, vp.z, acc.z); acc.w = fmaf(e3, vp.w, acc.w);

        kf = kn; pf = pn;
    }

    f32x4 o;
    o.x = __fdividef(acc.x, lsum.x); o.y = __fdividef(acc.y, lsum.y);
    o.z = __fdividef(acc.z, lsum.z); o.w = __fdividef(acc.w, lsum.w);
    *(f32x4*)(out + qoff) = o;
}

extern "C" void kernel_launch(void* const* d_in, const int* in_sizes, int n_in,
                              void* d_out, int out_size, void* d_ws, size_t ws_size,
                              hipStream_t stream) {
    const float* q  = (const float*)d_in[0];
    const float* k  = (const float*)d_in[1];
    const float* v  = (const float*)d_in[2];
    const float* pe = (const float*)d_in[3];
    const float* W1 = (const float*)d_in[4];
    const float* b1 = (const float*)d_in[5];
    const float* W2 = (const float*)d_in[6];
    // d_in[7] = b2: cancels in softmax over neighbors.
    float* out = (float*)d_out;
    float* ws  = (float*)d_ws;   // uses 2560 * 4 B = 10 KB

    pack_weights<<<1, 256, 0, stream>>>(W1, b1, W2, ws);

    const int nrows  = in_sizes[0] / 16;   // (bs*num_p)*4 heads = 262144
    const int groups = nrows / 16;         // 16384 wave-groups
    const int grid   = groups / 4;         // 4 waves per 256-thread block
    subattn_mfma<<<grid, 256, 0, stream>>>(q, k, v, pe, ws, out);
}

// Round 14
// 116.579 us; speedup vs baseline: 1.0283x; 1.0283x over previous
//
#include <hip/hip_runtime.h>

typedef unsigned int uint;
typedef unsigned short ushort;
typedef __attribute__((ext_vector_type(4))) uint   u32x4;
typedef __attribute__((ext_vector_type(8))) short  short8;
typedef __attribute__((ext_vector_type(8))) __bf16 bf16x8;
typedef __attribute__((ext_vector_type(4))) float  f32x4;

// Device pass: real gfx950 builtin. Host pass: inert asm fallback (never codegen'd).
__device__ __forceinline__ f32x4 mfma32(short8 a, short8 b, f32x4 c){
#if __has_builtin(__builtin_amdgcn_mfma_f32_16x16x32_bf16)
    return __builtin_amdgcn_mfma_f32_16x16x32_bf16(
        __builtin_bit_cast(bf16x8, a), __builtin_bit_cast(bf16x8, b), c, 0, 0, 0);
#else
    asm volatile("v_mfma_f32_16x16x32_bf16 %0, %1, %2, %0\n\ts_nop 7\n\ts_nop 7"
                 : "+v"(c) : "v"(a), "v"(b));
    return c;
#endif
}

__device__ __forceinline__ uint  fbits(float f){ return __builtin_bit_cast(uint, f); }
__device__ __forceinline__ float ibits(uint u){ return __builtin_bit_cast(float, u); }
__device__ __forceinline__ ushort rne_bf16(float f){
    uint u = fbits(f);
    return (ushort)((u + 0x7FFFu + ((u >> 16) & 1u)) >> 16);
}
// packed 2xf32 -> 2xbf16 (low = a, high = b); single HW op on gfx950
__device__ __forceinline__ uint cvtpk(float a, float b){
    uint r;
    asm("v_cvt_pk_bf16_f32 %0, %1, %2" : "=v"(r) : "v"(a), "v"(b));
    return r;
}

// ---------------- weight packing into per-lane K=32 MFMA fragments ----------------
// Slot convention (valid because A and B share the same (g,e)->k map, so the HW
// k-permutation cancels): slot (g=lane>>4, e=0..7) of the K=32 operand.
//  A1[t]: slot e -> channel c = 4g+(e&3); part = (e<4) ? hi : lo of W1[c][16t+m]
//  A2[p]: slot e -> hidden  = 16*(2p+(e>>2)) + 4g + (e&3); value = bf16(W2[hid][m])
//  b1f[t]: f32x4 = b1[16t+4g+r]  (C-in bias for layer 1)
__global__ void pack_weights(const float* __restrict__ W1, const float* __restrict__ b1,
                             const float* __restrict__ W2, float* __restrict__ ws)
{
    const int e4 = threadIdx.x;         // 256 = 4 tiles * 64 lanes
    const int t = e4 >> 6, l = e4 & 63;
    const int g = l >> 4, m = l & 15;
    uint* wsu = (uint*)ws;

    ushort el[8];
    #pragma unroll
    for (int i = 0; i < 8; ++i) {
        const int c = 4*g + (i & 3);
        const float w = W1[c * 64 + 16*t + m];   // W1 is (16,64) row-major
        const ushort hi = rne_bf16(w);
        if (i < 4) el[i] = hi;
        else       el[i] = rne_bf16(w - ibits(((uint)hi) << 16));  // lo residual
    }
    #pragma unroll
    for (int r = 0; r < 4; ++r)
        wsu[(t*64 + l)*4 + r] = (uint)el[2*r] | ((uint)el[2*r+1] << 16);

    if (t < 2) {
        const int p = t;
        ushort e2[8];
        #pragma unroll
        for (int i = 0; i < 8; ++i) {
            const int hid = 16*(2*p + (i >> 2)) + 4*g + (i & 3);
            e2[i] = rne_bf16(W2[hid * 16 + m]);  // W2 is (64,16) row-major
        }
        #pragma unroll
        for (int r = 0; r < 4; ++r)
            wsu[1024 + (p*64 + l)*4 + r] = (uint)e2[2*r] | ((uint)e2[2*r+1] << 16);
    }

    #pragma unroll
    for (int r = 0; r < 4; ++r)
        ws[1536 + (t*64 + l)*4 + r] = b1[16*t + 4*g + r];
}

// ---------------- main kernel ----------------
// One wave = 16 rows; lane (n=l&15, g=l>>4) owns row n, channel window 4g..4g+3.
// Per neighbor: 4 independent K=32 MFMAs (W1 hi+lo in the two K-halves), relu +
// cvt_pk, 2 chained K=32 MFMAs whose B-fragment is exactly the packed layer-1
// output -- zero cross-lane movement. 6 MFMAs/neighbor.
// ROUND 14: r9 body (proven, 97us) + waves_per_eu(6) occupancy, with r12's
// failure mode closed: the per-iteration empty-asm PIN forces the weight
// fragments + q to stay in VGPRs, so the allocator cannot demote them and
// re-fetch per iteration (r12: VGPR=40, FETCH +25MB, 120us). Expected ~56-64
// VGPR -> 8 waves/EU resident, doubling the TLP feeding the per-CU miss queue
// (delivery measured at 8.2 B/cyc/CU vs the 10.2 streaming ceiling).
__global__ __launch_bounds__(256) __attribute__((amdgpu_waves_per_eu(6)))
void subattn_mfma(const float* __restrict__ q, const float* __restrict__ k,
                  const float* __restrict__ v, const float* __restrict__ pe,
                  const float* __restrict__ ws, float* __restrict__ out)
{
    const int tid = threadIdx.x;
    const int wv  = tid >> 6;
    const int l   = tid & 63;
    const int n   = l & 15, g = l >> 4;
    const int grp = blockIdx.x * 4 + wv;
    const int rg  = grp * 16 + n;            // global row = bp*4 + h
    const int bp  = rg >> 2, h = rg & 3;

    // weight fragments: A1 16 + A2 8 + b1f 16 = 40 VGPRs persistent
    const u32x4* a1p = (const u32x4*)ws;
    const u32x4* a2p = (const u32x4*)(ws + 1024);
    const f32x4* bfp = (const f32x4*)(ws + 1536);
    short8 a1[4], a2[2];
    f32x4  b1f[4];
    #pragma unroll
    for (int t = 0; t < 4; ++t) {
        a1[t]  = __builtin_bit_cast(short8, a1p[t*64 + l]);
        b1f[t] = bfp[t*64 + l];
    }
    #pragma unroll
    for (int p = 0; p < 2; ++p) a2[p] = __builtin_bit_cast(short8, a2p[p*64 + l]);

    const size_t qoff = (size_t)rg * 16 + g * 4;
    f32x4 qf = *(const f32x4*)(q + qoff);
    const size_t kbase = (size_t)bp * 576 + h * 16 + g * 4;   // 9*64 per bp

    f32x4 lsum = {0.f, 0.f, 0.f, 0.f};
    f32x4 acc  = {0.f, 0.f, 0.f, 0.f};

    // 1-deep pipeline: k/pe of neighbor 0
    f32x4 kf = *(const f32x4*)(k  + kbase);
    f32x4 pf = *(const f32x4*)(pe + kbase);

    for (int j = 0; j < 9; ++j) {
        // PIN: force weights + q to stay register-resident this iteration.
        // Without this, waves_per_eu(6) makes the allocator demote them and
        // re-fetch from memory every iteration (r12: +25MB FETCH, 23% slower).
        asm volatile("" : "+v"(a1[0]), "+v"(a1[1]), "+v"(a1[2]), "+v"(a1[3]),
                          "+v"(a2[0]), "+v"(a2[1]),
                          "+v"(b1f[0]), "+v"(b1f[1]), "+v"(b1f[2]), "+v"(b1f[3]),
                          "+v"(qf));

        f32x4 kn, pn;
        if (j < 8) {
            const size_t noff = kbase + (size_t)(j + 1) * 64;
            kn = *(const f32x4*)(k  + noff);
            pn = *(const f32x4*)(pe + noff);
        }
        const f32x4 vf = *(const f32x4*)(v + kbase + (size_t)j * 64);

        const f32x4 x = qf - kf + pf;
        const uint xp0 = cvtpk(x.x, x.y);
        const uint xp1 = cvtpk(x.z, x.w);
        const u32x4 bxu = {xp0, xp1, xp0, xp1};        // [x_hi | x_hi] K-halves
        const short8 bx = __builtin_bit_cast(short8, bxu);

        // layer 1: 4 independent MFMAs, bias as C-in
        f32x4 c1_0 = mfma32(a1[0], bx, b1f[0]);
        f32x4 c1_1 = mfma32(a1[1], bx, b1f[1]);
        f32x4 c1_2 = mfma32(a1[2], bx, b1f[2]);
        f32x4 c1_3 = mfma32(a1[3], bx, b1f[3]);

        // relu + pack to bf16: ph[t] = h[n][16t+4g+{0,1,2,3}]
        const uint ph00 = cvtpk(fmaxf(c1_0.x, 0.f), fmaxf(c1_0.y, 0.f));
        const uint ph01 = cvtpk(fmaxf(c1_0.z, 0.f), fmaxf(c1_0.w, 0.f));
        const uint ph10 = cvtpk(fmaxf(c1_1.x, 0.f), fmaxf(c1_1.y, 0.f));
        const uint ph11 = cvtpk(fmaxf(c1_1.z, 0.f), fmaxf(c1_1.w, 0.f));
        const uint ph20 = cvtpk(fmaxf(c1_2.x, 0.f), fmaxf(c1_2.y, 0.f));
        const uint ph21 = cvtpk(fmaxf(c1_2.z, 0.f), fmaxf(c1_2.w, 0.f));
        const uint ph30 = cvtpk(fmaxf(c1_3.x, 0.f), fmaxf(c1_3.y, 0.f));
        const uint ph31 = cvtpk(fmaxf(c1_3.z, 0.f), fmaxf(c1_3.w, 0.f));

        // layer 2: B-fragment = concatenated layer-1 outputs (no shuffles)
        const u32x4 bh0u = {ph00, ph01, ph10, ph11};
        const u32x4 bh1u = {ph20, ph21, ph30, ph31};
        f32x4 c2 = {0.f, 0.f, 0.f, 0.f};
        c2 = mfma32(a2[0], __builtin_bit_cast(short8, bh0u), c2);
        c2 = mfma32(a2[1], __builtin_bit_cast(short8, bh1u), c2);
        // b2 omitted: softmax over neighbors is shift-invariant in b2.

        const f32x4 vp = vf + pf;
        const float e0 = __expf(c2.x), e1 = __expf(c2.y);
        const float e2 = __expf(c2.z), e3 = __expf(c2.w);
        lsum.x += e0; lsum.y += e1; lsum.z += e2; lsum.w += e3;
        acc.x = fmaf(e0, vp.x, acc.x); acc.y = fmaf(e1, vp.y, acc.y);
        acc.z = fmaf(e2, vp.z, acc.z); acc.w = fmaf(e3, vp.w, acc.w);

        kf = kn; pf = pn;
    }

    f32x4 o;
    o.x = __fdividef(acc.x, lsum.x); o.y = __fdividef(acc.y, lsum.y);
    o.z = __fdividef(acc.z, lsum.z); o.w = __fdividef(acc.w, lsum.w);
    *(f32x4*)(out + qoff) = o;
}

extern "C" void kernel_launch(void* const* d_in, const int* in_sizes, int n_in,
                              void* d_out, int out_size, void* d_ws, size_t ws_size,
                              hipStream_t stream) {
    const float* q  = (const float*)d_in[0];
    const float* k  = (const float*)d_in[1];
    const float* v  = (const float*)d_in[2];
    const float* pe = (const float*)d_in[3];
    const float* W1 = (const float*)d_in[4];
    const float* b1 = (const float*)d_in[5];
    const float* W2 = (const float*)d_in[6];
    // d_in[7] = b2: cancels in softmax over neighbors.
    float* out = (float*)d_out;
    float* ws  = (float*)d_ws;   // uses 2560 * 4 B = 10 KB

    pack_weights<<<1, 256, 0, stream>>>(W1, b1, W2, ws);

    const int nrows  = in_sizes[0] / 16;   // (bs*num_p)*4 heads = 262144
    const int groups = nrows / 16;         // 16384 wave-groups
    const int grid   = groups / 4;         // 4 waves per 256-thread block
    subattn_mfma<<<grid, 256, 0, stream>>>(q, k, v, pe, ws, out);
}

// Round 15
// 98.750 us; speedup vs baseline: 1.2140x; 1.1806x over previous
//
#include <hip/hip_runtime.h>

typedef unsigned int uint;
typedef unsigned short ushort;
typedef __attribute__((ext_vector_type(4))) uint   u32x4;
typedef __attribute__((ext_vector_type(8))) short  short8;
typedef __attribute__((ext_vector_type(8))) __bf16 bf16x8;
typedef __attribute__((ext_vector_type(4))) float  f32x4;

// Device pass: real gfx950 builtin. Host pass: inert asm fallback (never codegen'd).
__device__ __forceinline__ f32x4 mfma32(short8 a, short8 b, f32x4 c){
#if __has_builtin(__builtin_amdgcn_mfma_f32_16x16x32_bf16)
    return __builtin_amdgcn_mfma_f32_16x16x32_bf16(
        __builtin_bit_cast(bf16x8, a), __builtin_bit_cast(bf16x8, b), c, 0, 0, 0);
#else
    asm volatile("v_mfma_f32_16x16x32_bf16 %0, %1, %2, %0\n\ts_nop 7\n\ts_nop 7"
                 : "+v"(c) : "v"(a), "v"(b));
    return c;
#endif
}

__device__ __forceinline__ uint  fbits(float f){ return __builtin_bit_cast(uint, f); }
__device__ __forceinline__ float ibits(uint u){ return __builtin_bit_cast(float, u); }
__device__ __forceinline__ ushort rne_bf16(float f){
    uint u = fbits(f);
    return (ushort)((u + 0x7FFFu + ((u >> 16) & 1u)) >> 16);
}
// packed 2xf32 -> 2xbf16 (low = a, high = b); single HW op on gfx950
__device__ __forceinline__ uint cvtpk(float a, float b){
    uint r;
    asm("v_cvt_pk_bf16_f32 %0, %1, %2" : "=v"(r) : "v"(a), "v"(b));
    return r;
}

// ---------------- weight packing into per-lane K=32 MFMA fragments ----------------
// Slot convention (valid because A and B share the same (g,e)->k map, so the HW
// k-permutation cancels): slot (g=lane>>4, e=0..7) of the K=32 operand.
//  A1[t]: slot e -> channel c = 4g+(e&3); part = (e<4) ? hi : lo of W1[c][16t+m]
//  A2[p]: slot e -> hidden  = 16*(2p+(e>>2)) + 4g + (e&3); value = bf16(W2[hid][m])
//  b1f[t]: f32x4 = b1[16t+4g+r]
// ws as u32x4 units: [0..255] A1 (t*64+l); [256..383] A2 (p*64+l);
//                    [384..639] b1f (t*64+l)
__global__ void pack_weights(const float* __restrict__ W1, const float* __restrict__ b1,
                             const float* __restrict__ W2, float* __restrict__ ws)
{
    const int e4 = threadIdx.x;         // 256 = 4 tiles * 64 lanes
    const int t = e4 >> 6, l = e4 & 63;
    const int g = l >> 4, m = l & 15;
    uint* wsu = (uint*)ws;

    ushort el[8];
    #pragma unroll
    for (int i = 0; i < 8; ++i) {
        const int c = 4*g + (i & 3);
        const float w = W1[c * 64 + 16*t + m];   // W1 is (16,64) row-major
        const ushort hi = rne_bf16(w);
        if (i < 4) el[i] = hi;
        else       el[i] = rne_bf16(w - ibits(((uint)hi) << 16));  // lo residual
    }
    #pragma unroll
    for (int r = 0; r < 4; ++r)
        wsu[(t*64 + l)*4 + r] = (uint)el[2*r] | ((uint)el[2*r+1] << 16);

    if (t < 2) {
        const int p = t;
        ushort e2[8];
        #pragma unroll
        for (int i = 0; i < 8; ++i) {
            const int hid = 16*(2*p + (i >> 2)) + 4*g + (i & 3);
            e2[i] = rne_bf16(W2[hid * 16 + m]);  // W2 is (64,16) row-major
        }
        #pragma unroll
        for (int r = 0; r < 4; ++r)
            wsu[1024 + (p*64 + l)*4 + r] = (uint)e2[2*r] | ((uint)e2[2*r+1] << 16);
    }

    #pragma unroll
    for (int r = 0; r < 4; ++r)
        ws[1536 + (t*64 + l)*4 + r] = b1[16*t + 4*g + r];
}

// ---------------- main kernel ----------------
// One wave = 16 rows; lane (n=l&15, g=l>>4) owns row n, channel window 4g..4g+3.
// 6 MFMAs/neighbor (K=32, W1 hi+lo in the two K-halves; layer-1 C output packs
// directly into layer-2's B fragment -- zero cross-lane movement).
// ROUND 15: weights live in LDS, re-read every iteration (per-iteration memory
// clobber makes hoisting illegal) -- removes the 40-VGPR block the allocator
// kept demoting/spilling in r12/r14. Live set ~70 regs; waves_per_eu(6) gives
// 24 waves/CU (1.5x the TLP of the 97us r9 baseline) with NO spill pressure.
// This isolates the occupancy variable cleanly. LDS reads: 10 ds_read_b128 per
// iter, contiguous 1KB per read, conflict-free; ~16 TB/s aggregate (23% of
// LDS ceiling). Tripwires: WRITE_SIZE>17MB = spills; FETCH>240MB = refetch.
__global__ __launch_bounds__(256) __attribute__((amdgpu_waves_per_eu(6)))
void subattn_mfma(const float* __restrict__ q, const float* __restrict__ k,
                  const float* __restrict__ v, const float* __restrict__ pe,
                  const float* __restrict__ ws, float* __restrict__ out)
{
    __shared__ u32x4 ldsW[640];   // 10 KB: A1[256] | A2[128] | b1f[256]

    const int tid = threadIdx.x;
    const int wv  = tid >> 6;
    const int l   = tid & 63;
    const int n   = l & 15, g = l >> 4;
    const int grp = blockIdx.x * 4 + wv;
    const int rg  = grp * 16 + n;            // global row = bp*4 + h
    const int bp  = rg >> 2, h = rg & 3;

    // stage packed weights into LDS once per block
    for (int i = tid; i < 640; i += 256) ldsW[i] = ((const u32x4*)ws)[i];
    __syncthreads();

    const size_t qoff = (size_t)rg * 16 + g * 4;
    f32x4 qf = *(const f32x4*)(q + qoff);
    const size_t kbase = (size_t)bp * 576 + h * 16 + g * 4;   // 9*64 per bp

    f32x4 lsum = {0.f, 0.f, 0.f, 0.f};
    f32x4 acc  = {0.f, 0.f, 0.f, 0.f};

    // 1-deep pipeline: k/pe of neighbor 0
    f32x4 kf = *(const f32x4*)(k  + kbase);
    f32x4 pf = *(const f32x4*)(pe + kbase);

    const u32x4* wl = ldsW + l;   // per-lane base into fragments

    for (int j = 0; j < 9; ++j) {
        // memory clobber: LDS weight reads below cannot be hoisted/CSE'd out of
        // the loop, so they never occupy persistent registers (r12/r14 fix).
        asm volatile("" ::: "memory");
        asm volatile("" : "+v"(qf));   // keep q register-resident

        f32x4 kn, pn;
        if (j < 8) {
            const size_t noff = kbase + (size_t)(j + 1) * 64;
            kn = *(const f32x4*)(k  + noff);
            pn = *(const f32x4*)(pe + noff);
        }
        const f32x4 vf = *(const f32x4*)(v + kbase + (size_t)j * 64);

        const f32x4 x = qf - kf + pf;
        const uint xp0 = cvtpk(x.x, x.y);
        const uint xp1 = cvtpk(x.z, x.w);
        const u32x4 bxu = {xp0, xp1, xp0, xp1};        // [x_hi | x_hi] K-halves
        const short8 bx = __builtin_bit_cast(short8, bxu);

        // layer 1: 4 independent MFMAs; weights + bias read from LDS per tile
        const short8 a1t0 = __builtin_bit_cast(short8, wl[0]);
        const f32x4  b1t0 = __builtin_bit_cast(f32x4,  wl[384]);
        f32x4 c1_0 = mfma32(a1t0, bx, b1t0);
        const short8 a1t1 = __builtin_bit_cast(short8, wl[64]);
        const f32x4  b1t1 = __builtin_bit_cast(f32x4,  wl[448]);
        f32x4 c1_1 = mfma32(a1t1, bx, b1t1);
        const short8 a1t2 = __builtin_bit_cast(short8, wl[128]);
        const f32x4  b1t2 = __builtin_bit_cast(f32x4,  wl[512]);
        f32x4 c1_2 = mfma32(a1t2, bx, b1t2);
        const short8 a1t3 = __builtin_bit_cast(short8, wl[192]);
        const f32x4  b1t3 = __builtin_bit_cast(f32x4,  wl[576]);
        f32x4 c1_3 = mfma32(a1t3, bx, b1t3);

        // relu + pack to bf16: ph[t] = h[n][16t+4g+{0,1,2,3}]
        const uint ph00 = cvtpk(fmaxf(c1_0.x, 0.f), fmaxf(c1_0.y, 0.f));
        const uint ph01 = cvtpk(fmaxf(c1_0.z, 0.f), fmaxf(c1_0.w, 0.f));
        const uint ph10 = cvtpk(fmaxf(c1_1.x, 0.f), fmaxf(c1_1.y, 0.f));
        const uint ph11 = cvtpk(fmaxf(c1_1.z, 0.f), fmaxf(c1_1.w, 0.f));
        const uint ph20 = cvtpk(fmaxf(c1_2.x, 0.f), fmaxf(c1_2.y, 0.f));
        const uint ph21 = cvtpk(fmaxf(c1_2.z, 0.f), fmaxf(c1_2.w, 0.f));
        const uint ph30 = cvtpk(fmaxf(c1_3.x, 0.f), fmaxf(c1_3.y, 0.f));
        const uint ph31 = cvtpk(fmaxf(c1_3.z, 0.f), fmaxf(c1_3.w, 0.f));

        // layer 2: B-fragment = concatenated layer-1 outputs (no shuffles)
        const u32x4 bh0u = {ph00, ph01, ph10, ph11};
        const u32x4 bh1u = {ph20, ph21, ph30, ph31};
        const short8 a2t0 = __builtin_bit_cast(short8, wl[256]);
        const short8 a2t1 = __builtin_bit_cast(short8, wl[320]);
        f32x4 c2 = {0.f, 0.f, 0.f, 0.f};
        c2 = mfma32(a2t0, __builtin_bit_cast(short8, bh0u), c2);
        c2 = mfma32(a2t1, __builtin_bit_cast(short8, bh1u), c2);
        // b2 omitted: softmax over neighbors is shift-invariant in b2.

        const f32x4 vp = vf + pf;
        const float e0 = __expf(c2.x), e1 = __expf(c2.y);
        const float e2 = __expf(c2.z), e3 = __expf(c2.w);
        lsum.x += e0; lsum.y += e1; lsum.z += e2; lsum.w += e3;
        acc.x = fmaf(e0, vp.x, acc.x); acc.y = fmaf(e1, vp.y, acc.y);
        acc.z = fmaf(e2, vp.z, acc.z); acc.w = fmaf(e3, vp.w, acc.w);

        kf = kn; pf = pn;
    }

    f32x4 o;
    o.x = __fdividef(acc.x, lsum.x); o.y = __fdividef(acc.y, lsum.y);
    o.z = __fdividef(acc.z, lsum.z); o.w = __fdividef(acc.w, lsum.w);
    *(f32x4*)(out + qoff) = o;
}

extern "C" void kernel_launch(void* const* d_in, const int* in_sizes, int n_in,
                              void* d_out, int out_size, void* d_ws, size_t ws_size,
                              hipStream_t stream) {
    const float* q  = (const float*)d_in[0];
    const float* k  = (const float*)d_in[1];
    const float* v  = (const float*)d_in[2];
    const float* pe = (const float*)d_in[3];
    const float* W1 = (const float*)d_in[4];
    const float* b1 = (const float*)d_in[5];
    const float* W2 = (const float*)d_in[6];
    // d_in[7] = b2: cancels in softmax over neighbors.
    float* out = (float*)d_out;
    float* ws  = (float*)d_ws;   // uses 2560 * 4 B = 10 KB

    pack_weights<<<1, 256, 0, stream>>>(W1, b1, W2, ws);

    const int nrows  = in_sizes[0] / 16;   // (bs*num_p)*4 heads = 262144
    const int groups = nrows / 16;         // 16384 wave-groups
    const int grid   = groups / 4;         // 4 waves per 256-thread block
    subattn_mfma<<<grid, 256, 0, stream>>>(q, k, v, pe, ws, out);
}